// Round 3
// baseline (1638.101 us; speedup 1.0000x reference)
//
#include <hip/hip_runtime.h>

// ---------------------------------------------------------------------------
// DecoderBlock on MI355X (gfx950).  B=2, L=2048, D=2048, H=16, DH=128, FF=8192
// Round 3: attention overhaul.
//  - q-tile pairing (x, 31-x): uniform 33-iteration blocks, zero causal tail
//  - V LDS double-buffered, T3 2-phase schedule (1 barrier/iter)
//  - V granule-XOR swizzle, pre-applied in v_transpose global write (rule #21)
//  - K fragments in registers direct from global/L2
//  - setprio(1) around MFMA clusters (T5)
// GEMMs / norms / rope unchanged from the passing round-2 kernel.
// ---------------------------------------------------------------------------

typedef __bf16 bf16;
typedef __bf16 bf16x8 __attribute__((ext_vector_type(8)));
typedef float  f32x4  __attribute__((ext_vector_type(4)));

__device__ __forceinline__ void gload16(const void* g, void* l) {
  __builtin_amdgcn_global_load_lds((const __attribute__((address_space(1))) void*)g,
                                   (__attribute__((address_space(3))) void*)l,
                                   16, 0, 0);
}

// ------------------------------ RMSNorm (f32 -> bf16) ----------------------
__global__ __launch_bounds__(256) void rmsnorm_to_bf16(
    const float* __restrict__ x, const float* __restrict__ w, bf16* __restrict__ out)
{
  const int D = 2048;
  const int row = blockIdx.x;
  const int tid = threadIdx.x;
  const float* xr = x + (size_t)row * D;
  float4 a = ((const float4*)xr)[tid * 2];
  float4 c = ((const float4*)xr)[tid * 2 + 1];
  float ss = a.x*a.x + a.y*a.y + a.z*a.z + a.w*a.w
           + c.x*c.x + c.y*c.y + c.z*c.z + c.w*c.w;
  #pragma unroll
  for (int m = 1; m < 64; m <<= 1) ss += __shfl_xor(ss, m, 64);
  __shared__ float red[4];
  if ((tid & 63) == 0) red[tid >> 6] = ss;
  __syncthreads();
  float tot = red[0] + red[1] + red[2] + red[3];
  float rms = rsqrtf(tot * (1.0f / D) + 1.1920929e-7f);
  const float* wr = w + tid * 8;
  float vals[8] = {a.x, a.y, a.z, a.w, c.x, c.y, c.z, c.w};
  bf16x8 o;
  #pragma unroll
  for (int j = 0; j < 8; ++j) o[j] = (bf16)(vals[j] * rms * wr[j]);
  *(bf16x8*)(out + (size_t)row * D + tid * 8) = o;
}

// --------------------- transpose + convert f32[R][C] -> bf16[C][R] ---------
__global__ __launch_bounds__(256) void transpose_to_bf16(
    const float* __restrict__ in, bf16* __restrict__ out, int R, int C)
{
  __shared__ float tile[32][33];
  const int tx = threadIdx.x, ty = threadIdx.y;      // 32 x 8
  const int c0 = blockIdx.x * 32, r0 = blockIdx.y * 32;
  #pragma unroll
  for (int i = 0; i < 4; ++i)
    tile[ty + i * 8][tx] = in[(size_t)(r0 + ty + i * 8) * C + c0 + tx];
  __syncthreads();
  #pragma unroll
  for (int i = 0; i < 4; ++i)
    out[(size_t)(c0 + ty + i * 8) * R + r0 + tx] = (bf16)tile[tx][ty + i * 8];
}

// --------------- V[b*L+key][h*128+dh] -> VT[(bh*128+dh)][key'] (bf16) ------
// key' is granule-XOR swizzled WITHIN each 64-key block:
//   key' = (key & ~63) | ((((key>>3)&7) ^ (dh&7)) << 3) | (key & 7)
// so that a linear global_load_lds stage + XOR-read in attn is conflict-free.
__global__ __launch_bounds__(256) void v_transpose(
    const bf16* __restrict__ v, bf16* __restrict__ vt)
{
  const int L = 2048, DM = 2048;
  __shared__ bf16 tile[32][33];
  const int tx = threadIdx.x, ty = threadIdx.y;      // 32 x 8
  const int k0 = blockIdx.x * 32;                    // key block
  const int d0 = blockIdx.y * 32;                    // dh block
  const int bh = blockIdx.z;
  const int b = bh >> 4, h = bh & 15;
  #pragma unroll
  for (int i = 0; i < 4; ++i)
    tile[ty + i * 8][tx] = v[(size_t)(b * L + k0 + ty + i * 8) * DM + h * 128 + d0 + tx];
  __syncthreads();
  #pragma unroll
  for (int i = 0; i < 4; ++i) {
    const int d = d0 + ty + i * 8;
    const int key = k0 + tx;
    const int keysw = (key & ~63) | (((((key >> 3) & 7) ^ (d & 7)) << 3)) | (key & 7);
    vt[(size_t)(bh * 128 + d) * L + keysw] = tile[tx][ty + i * 8];
  }
}

// ------------------------------ GEMM: C = A[M,K] * Bt[N,K]^T ----------------
// Linear LDS staging (m97 structure).  EPI: 0 bf16; 1 f32 + resid; 2 silu bf16
template<int EPI>
__global__ __launch_bounds__(256, 2) void gemm_bt(
    const bf16* __restrict__ A, const bf16* __restrict__ Bt,
    void* Cout, const float* resid, int M, int N, int K)
{
  __shared__ bf16 sA[128 * 64];
  __shared__ bf16 sB[128 * 64];

  const int tid = threadIdx.x;
  const int lane = tid & 63;
  const int w = tid >> 6;
  const int wm = w >> 1, wn = w & 1;
  const int lo = lane & 15, hi = lane >> 4;

  const int nbn = N >> 7;
  const int nwg = gridDim.x;
  const int bid = blockIdx.x;
  int swz = bid;
  if ((nwg & 7) == 0) { const int cpx = nwg >> 3; swz = (bid & 7) * cpx + (bid >> 3); }
  const int bm = swz / nbn, bn = swz % nbn;

  const bf16* aptr[4];
  const bf16* bptr[4];
  #pragma unroll
  for (int i = 0; i < 4; ++i) {
    const int g = i * 256 + tid;
    const int row = g >> 3, gr = g & 7;
    aptr[i] = A  + (size_t)(bm * 128 + row) * K + gr * 8;
    bptr[i] = Bt + (size_t)(bn * 128 + row) * K + gr * 8;
  }

  f32x4 acc[4][4] = {};
  const int nkt = K >> 6;
  for (int kt = 0; kt < nkt; ++kt) {
    #pragma unroll
    for (int i = 0; i < 4; ++i) {
      gload16(aptr[i] + kt * 64, &sA[(i * 256 + w * 64) * 8]);
      gload16(bptr[i] + kt * 64, &sB[(i * 256 + w * 64) * 8]);
    }
    __syncthreads();
    #pragma unroll
    for (int ks = 0; ks < 2; ++ks) {
      bf16x8 af[4], bfm[4];
      #pragma unroll
      for (int mi = 0; mi < 4; ++mi)
        af[mi] = *(const bf16x8*)&sA[(wm * 64 + mi * 16 + lo) * 64 + ks * 32 + hi * 8];
      #pragma unroll
      for (int ni = 0; ni < 4; ++ni)
        bfm[ni] = *(const bf16x8*)&sB[(wn * 64 + ni * 16 + lo) * 64 + ks * 32 + hi * 8];
      #pragma unroll
      for (int mi = 0; mi < 4; ++mi)
        #pragma unroll
        for (int ni = 0; ni < 4; ++ni)
          acc[mi][ni] = __builtin_amdgcn_mfma_f32_16x16x32_bf16(af[mi], bfm[ni], acc[mi][ni], 0, 0, 0);
    }
    __syncthreads();
  }

  #pragma unroll
  for (int mi = 0; mi < 4; ++mi) {
    #pragma unroll
    for (int j = 0; j < 4; ++j) {
      const size_t row = (size_t)(bm * 128 + wm * 64 + mi * 16 + hi * 4 + j);
      const size_t ro = row * (size_t)N;
      #pragma unroll
      for (int ni = 0; ni < 4; ++ni) {
        const int col = bn * 128 + wn * 64 + ni * 16 + lo;
        const float v = acc[mi][ni][j];
        if constexpr (EPI == 0) {
          ((bf16*)Cout)[ro + col] = (bf16)v;
        } else if constexpr (EPI == 1) {
          ((float*)Cout)[ro + col] = v + resid[ro + col];
        } else {
          ((bf16*)Cout)[ro + col] = (bf16)(v / (1.0f + __expf(-v)));
        }
      }
    }
  }
}

// ------------------------------ RoPE on q,k (in-place, bf16) ---------------
__global__ __launch_bounds__(256) void rope_qk(
    bf16* q, bf16* k, const float* __restrict__ cs, const float* __restrict__ sn)
{
  const int L = 2048, DM = 2048;
  const int idx = blockIdx.x * 256 + threadIdx.x;
  const int m = idx >> 7;
  const int rem = idx & 127;
  const int h = rem >> 3, t8 = rem & 7;
  const int pos = m & (L - 1);
  const int d0 = t8 * 8;
  const float* cb = cs + (size_t)pos * 128 + d0;
  const float* sb = sn + (size_t)pos * 128 + d0;
  float4 c1a = *(const float4*)(cb);      float4 c1b = *(const float4*)(cb + 4);
  float4 c2a = *(const float4*)(cb + 64); float4 c2b = *(const float4*)(cb + 68);
  float4 s1a = *(const float4*)(sb);      float4 s1b = *(const float4*)(sb + 4);
  float4 s2a = *(const float4*)(sb + 64); float4 s2b = *(const float4*)(sb + 68);
  float c1[8] = {c1a.x,c1a.y,c1a.z,c1a.w,c1b.x,c1b.y,c1b.z,c1b.w};
  float c2[8] = {c2a.x,c2a.y,c2a.z,c2a.w,c2b.x,c2b.y,c2b.z,c2b.w};
  float s1[8] = {s1a.x,s1a.y,s1a.z,s1a.w,s1b.x,s1b.y,s1b.z,s1b.w};
  float s2[8] = {s2a.x,s2a.y,s2a.z,s2a.w,s2b.x,s2b.y,s2b.z,s2b.w};
  const size_t base = (size_t)m * DM + h * 128 + d0;
  #pragma unroll
  for (int t = 0; t < 2; ++t) {
    bf16* buf = t ? k : q;
    bf16x8 x1 = *(bf16x8*)(buf + base);
    bf16x8 x2 = *(bf16x8*)(buf + base + 64);
    bf16x8 o1, o2;
    #pragma unroll
    for (int j = 0; j < 8; ++j) {
      const float a = (float)x1[j], b = (float)x2[j];
      o1[j] = (bf16)(a * c1[j] - b * s1[j]);
      o2[j] = (bf16)(b * c2[j] + a * s2[j]);
    }
    *(bf16x8*)(buf + base) = o1;
    *(bf16x8*)(buf + base + 64) = o2;
  }
}

// ------------------------------ Flash attention ----------------------------
// grid (16, B*H), 256 thr.  Block xp handles q-tiles tA=xp and tB=31-xp
// (uniform 33 kt-iterations).  Wave w owns rows [tile*64+w*16, +16).
// V double-buffered in LDS with granule-XOR swizzle (pre-applied in VT).
__global__ __launch_bounds__(256, 2) void attn_fwd(
    const bf16* __restrict__ Q, const bf16* __restrict__ Kb,
    const bf16* __restrict__ VT, const int* __restrict__ mask,
    bf16* __restrict__ O)
{
  const int L = 2048, DM = 2048;
  __shared__ bf16 Vt[2][128 * 64];      // [buf][dh][key], swizzled granules
  __shared__ bf16 Plds[4][2][16 * 64];  // [wave][tile][qrow][key]

  const int tid = threadIdx.x, lane = tid & 63, w = tid >> 6;
  const int lo = lane & 15, hi = lane >> 4;
  const int s7 = lo & 7;
  const int xp = blockIdx.x;
  const int bh = blockIdx.y;
  const int b = bh >> 4, h = bh & 15;
  const int tA = xp, tB = 31 - xp;
  const int qrowA = tA * 64 + w * 16;
  const int qrowB = tB * 64 + w * 16;
  const float scale = 0.08838834764831845f;
  const float NEG_INF = -__builtin_inff();

  bf16x8 qfA[4], qfB[4];
  {
    const bf16* qa = Q + (size_t)(b * L + qrowA + lo) * DM + h * 128;
    const bf16* qc = Q + (size_t)(b * L + qrowB + lo) * DM + h * 128;
    #pragma unroll
    for (int ds = 0; ds < 4; ++ds) {
      qfA[ds] = *(const bf16x8*)(qa + ds * 32 + hi * 8);
      qfB[ds] = *(const bf16x8*)(qc + ds * 32 + hi * 8);
    }
  }

  float mA[4], lA[4], mB[4], lB[4];
  #pragma unroll
  for (int j = 0; j < 4; ++j) { mA[j] = NEG_INF; lA[j] = 0.f; mB[j] = NEG_INF; lB[j] = 0.f; }
  f32x4 oA[8] = {};
  f32x4 oB[8] = {};

  // staging sources: granule g = i*256+tid -> (dh row = g>>3, key-granule = g&7)
  const bf16* vsrc[4];
  #pragma unroll
  for (int i = 0; i < 4; ++i) {
    const int g = i * 256 + tid;
    const int row = g >> 3, gr = g & 7;
    vsrc[i] = VT + (size_t)(bh * 128 + row) * L + gr * 8;
  }

  // prologue: stage kt=0 into buf 0
  #pragma unroll
  for (int i = 0; i < 4; ++i)
    gload16(vsrc[i], &Vt[0][(i * 256 + w * 64) * 8]);
  __syncthreads();

  const int nkt = tB + 1;
  for (int kt = 0; kt < nkt; ++kt) {
    const int buf = kt & 1;
    if (kt + 1 < nkt) {
      #pragma unroll
      for (int i = 0; i < 4; ++i)
        gload16(vsrc[i] + (kt + 1) * 64, &Vt[buf ^ 1][(i * 256 + w * 64) * 8]);
    }
    const bool doA = (kt <= tA);

    int mk[4];
    #pragma unroll
    for (int kb = 0; kb < 4; ++kb) mk[kb] = mask[b * L + kt * 64 + kb * 16 + lo];

    // ---- QK^T (K frags direct from global/L2, registers) ----
    f32x4 SA[4], SB[4];
    const bf16* kbase = Kb + (size_t)(b * L + kt * 64 + lo) * DM + h * 128 + hi * 8;
    __builtin_amdgcn_s_setprio(1);
    #pragma unroll
    for (int kb = 0; kb < 4; ++kb) {
      bf16x8 kf[4];
      #pragma unroll
      for (int ds = 0; ds < 4; ++ds)
        kf[ds] = *(const bf16x8*)(kbase + (size_t)kb * 16 * DM + ds * 32);
      f32x4 sb_ = {};
      #pragma unroll
      for (int ds = 0; ds < 4; ++ds)
        sb_ = __builtin_amdgcn_mfma_f32_16x16x32_bf16(qfB[ds], kf[ds], sb_, 0, 0, 0);
      SB[kb] = sb_;
      if (doA) {
        f32x4 sa_ = {};
        #pragma unroll
        for (int ds = 0; ds < 4; ++ds)
          sa_ = __builtin_amdgcn_mfma_f32_16x16x32_bf16(qfA[ds], kf[ds], sa_, 0, 0, 0);
        SA[kb] = sa_;
      }
    }
    __builtin_amdgcn_s_setprio(0);

    // ---- mask + scale + online softmax + P write, tile B ----
    #pragma unroll
    for (int kb = 0; kb < 4; ++kb) {
      const int kidx = kt * 64 + kb * 16 + lo;
      #pragma unroll
      for (int j = 0; j < 4; ++j) {
        const float sv = SB[kb][j] * scale;
        SB[kb][j] = (mk[kb] != 0 && kidx <= qrowB + hi * 4 + j) ? sv : NEG_INF;
      }
    }
    {
      float p[4][4];
      #pragma unroll
      for (int j = 0; j < 4; ++j) {
        float tm = fmaxf(fmaxf(SB[0][j], SB[1][j]), fmaxf(SB[2][j], SB[3][j]));
        tm = fmaxf(tm, __shfl_xor(tm, 1, 64));
        tm = fmaxf(tm, __shfl_xor(tm, 2, 64));
        tm = fmaxf(tm, __shfl_xor(tm, 4, 64));
        tm = fmaxf(tm, __shfl_xor(tm, 8, 64));
        const float mn = fmaxf(mB[j], tm);
        const float mn2 = (mn == NEG_INF) ? 0.f : mn;
        const float alpha = __expf(mB[j] - mn2);
        float ps = 0.f;
        #pragma unroll
        for (int kb = 0; kb < 4; ++kb) { p[kb][j] = __expf(SB[kb][j] - mn2); ps += p[kb][j]; }
        ps += __shfl_xor(ps, 1, 64);
        ps += __shfl_xor(ps, 2, 64);
        ps += __shfl_xor(ps, 4, 64);
        ps += __shfl_xor(ps, 8, 64);
        lB[j] = lB[j] * alpha + ps;
        mB[j] = mn;
        #pragma unroll
        for (int n = 0; n < 8; ++n) oB[n][j] *= alpha;
      }
      #pragma unroll
      for (int kb = 0; kb < 4; ++kb)
        #pragma unroll
        for (int j = 0; j < 4; ++j)
          Plds[w][1][(hi * 4 + j) * 64 + kb * 16 + lo] = (bf16)p[kb][j];
    }

    // ---- tile A (when active) ----
    if (doA) {
      #pragma unroll
      for (int kb = 0; kb < 4; ++kb) {
        const int kidx = kt * 64 + kb * 16 + lo;
        #pragma unroll
        for (int j = 0; j < 4; ++j) {
          const float sv = SA[kb][j] * scale;
          SA[kb][j] = (mk[kb] != 0 && kidx <= qrowA + hi * 4 + j) ? sv : NEG_INF;
        }
      }
      float p[4][4];
      #pragma unroll
      for (int j = 0; j < 4; ++j) {
        float tm = fmaxf(fmaxf(SA[0][j], SA[1][j]), fmaxf(SA[2][j], SA[3][j]));
        tm = fmaxf(tm, __shfl_xor(tm, 1, 64));
        tm = fmaxf(tm, __shfl_xor(tm, 2, 64));
        tm = fmaxf(tm, __shfl_xor(tm, 4, 64));
        tm = fmaxf(tm, __shfl_xor(tm, 8, 64));
        const float mn = fmaxf(mA[j], tm);
        const float mn2 = (mn == NEG_INF) ? 0.f : mn;
        const float alpha = __expf(mA[j] - mn2);
        float ps = 0.f;
        #pragma unroll
        for (int kb = 0; kb < 4; ++kb) { p[kb][j] = __expf(SA[kb][j] - mn2); ps += p[kb][j]; }
        ps += __shfl_xor(ps, 1, 64);
        ps += __shfl_xor(ps, 2, 64);
        ps += __shfl_xor(ps, 4, 64);
        ps += __shfl_xor(ps, 8, 64);
        lA[j] = lA[j] * alpha + ps;
        mA[j] = mn;
        #pragma unroll
        for (int n = 0; n < 8; ++n) oA[n][j] *= alpha;
      }
      #pragma unroll
      for (int kb = 0; kb < 4; ++kb)
        #pragma unroll
        for (int j = 0; j < 4; ++j)
          Plds[w][0][(hi * 4 + j) * 64 + kb * 16 + lo] = (bf16)p[kb][j];
    }

    // ---- PV: shared V fragments feed both tiles ----
    __builtin_amdgcn_s_setprio(1);
    #pragma unroll
    for (int ks = 0; ks < 2; ++ks) {
      const bf16x8 paB = *(const bf16x8*)&Plds[w][1][lo * 64 + ks * 32 + hi * 8];
      bf16x8 paA = {};
      if (doA) paA = *(const bf16x8*)&Plds[w][0][lo * 64 + ks * 32 + hi * 8];
      #pragma unroll
      for (int n = 0; n < 8; ++n) {
        const int r = n * 16 + lo;
        const bf16x8 vf = *(const bf16x8*)&Vt[buf][r * 64 + (((ks * 4 + hi) ^ s7) << 3)];
        oB[n] = __builtin_amdgcn_mfma_f32_16x16x32_bf16(paB, vf, oB[n], 0, 0, 0);
        if (doA) oA[n] = __builtin_amdgcn_mfma_f32_16x16x32_bf16(paA, vf, oA[n], 0, 0, 0);
      }
    }
    __builtin_amdgcn_s_setprio(0);

    __syncthreads();
  }

  // epilogue: both tiles
  float invA[4], invB[4];
  #pragma unroll
  for (int j = 0; j < 4; ++j) {
    invA[j] = (lA[j] > 0.f) ? 1.f / lA[j] : 0.f;
    invB[j] = (lB[j] > 0.f) ? 1.f / lB[j] : 0.f;
  }
  bf16* oa = O + (size_t)(b * L + qrowA) * DM + h * 128;
  bf16* ob = O + (size_t)(b * L + qrowB) * DM + h * 128;
  #pragma unroll
  for (int n = 0; n < 8; ++n)
    #pragma unroll
    for (int j = 0; j < 4; ++j) {
      oa[(size_t)(hi * 4 + j) * DM + n * 16 + lo] = (bf16)(oA[n][j] * invA[j]);
      ob[(size_t)(hi * 4 + j) * DM + n * 16 + lo] = (bf16)(oB[n][j] * invB[j]);
    }
}

// ---------------------------------------------------------------------------
extern "C" void kernel_launch(void* const* d_in, const int* in_sizes, int n_in,
                              void* d_out, int out_size, void* d_ws, size_t ws_size,
                              hipStream_t stream)
{
  (void)in_sizes; (void)n_in; (void)out_size; (void)ws_size;
  const float* x        = (const float*)d_in[0];
  const float* rope_cos = (const float*)d_in[1];
  const float* rope_sin = (const float*)d_in[2];
  const int*   mask     = (const int*)d_in[3];
  const float* w_norm1  = (const float*)d_in[4];
  const float* w_norm2  = (const float*)d_in[5];
  const float* wq       = (const float*)d_in[6];
  const float* wk       = (const float*)d_in[7];
  const float* wv       = (const float*)d_in[8];
  const float* wo       = (const float*)d_in[9];
  const float* w_ff1    = (const float*)d_in[10];
  const float* w_ff2    = (const float*)d_in[11];
  float* out = (float*)d_out;

  const int M = 4096, D = 2048, FFD = 8192;
  char* ws = (char*)d_ws;
  const size_t WSLAB = 8388608ull;    // 2048*2048*2 B
  const size_t XNB   = 16777216ull;   // 4096*2048*2 B
  bf16* wqt  = (bf16*)(ws);
  bf16* wkt  = (bf16*)(ws + WSLAB);
  bf16* wvt  = (bf16*)(ws + 2 * WSLAB);
  bf16* wot  = (bf16*)(ws + 3 * WSLAB);
  char* pool = ws + 4 * WSLAB;
  bf16* xn   = (bf16*)(pool);
  bf16* qb   = (bf16*)(pool + XNB);
  bf16* kb   = (bf16*)(pool + 2 * XNB);
  bf16* vb   = (bf16*)(pool + 3 * XNB);
  bf16* ao   = (bf16*)(pool + 4 * XNB);
  bf16* vt   = (bf16*)(pool);               // reuses xn after QKV GEMMs
  bf16* ff1t = (bf16*)(ws);                 // reuses wq_t..wo_t after WO GEMM
  bf16* hmid = (bf16*)(pool);               // reuses vt|qb|kb|vb after attention
  bf16* ff2t = (bf16*)(ws);                 // reuses ff1_t after FF1
  bf16* xn2  = (bf16*)(pool + 4 * XNB);     // reuses ao after WO GEMM

  const dim3 tb(32, 8);

  rmsnorm_to_bf16<<<M, 256, 0, stream>>>(x, w_norm1, xn);
  transpose_to_bf16<<<dim3(D / 32, D / 32), tb, 0, stream>>>(wq, wqt, D, D);
  transpose_to_bf16<<<dim3(D / 32, D / 32), tb, 0, stream>>>(wk, wkt, D, D);
  transpose_to_bf16<<<dim3(D / 32, D / 32), tb, 0, stream>>>(wv, wvt, D, D);
  transpose_to_bf16<<<dim3(D / 32, D / 32), tb, 0, stream>>>(wo, wot, D, D);

  gemm_bt<0><<<(M / 128) * (D / 128), 256, 0, stream>>>(xn, wqt, qb, nullptr, M, D, D);
  gemm_bt<0><<<(M / 128) * (D / 128), 256, 0, stream>>>(xn, wkt, kb, nullptr, M, D, D);
  gemm_bt<0><<<(M / 128) * (D / 128), 256, 0, stream>>>(xn, wvt, vb, nullptr, M, D, D);

  rope_qk<<<2048, 256, 0, stream>>>(qb, kb, rope_cos, rope_sin);

  // xn dead from here; vt overwrites it
  v_transpose<<<dim3(2048 / 32, 128 / 32, 32), tb, 0, stream>>>(vb, vt);

  attn_fwd<<<dim3(16, 32), 256, 0, stream>>>(qb, kb, vt, mask, ao);

  gemm_bt<1><<<(M / 128) * (D / 128), 256, 0, stream>>>(ao, wot, out, x, M, D, D);

  rmsnorm_to_bf16<<<M, 256, 0, stream>>>(out, w_norm2, xn2);

  transpose_to_bf16<<<dim3(FFD / 32, D / 32), tb, 0, stream>>>(w_ff1, ff1t, D, FFD);
  gemm_bt<2><<<(M / 128) * (FFD / 128), 256, 0, stream>>>(xn2, ff1t, hmid, nullptr, M, FFD, D);

  transpose_to_bf16<<<dim3(D / 32, FFD / 32), tb, 0, stream>>>(w_ff2, ff2t, FFD, D);
  gemm_bt<1><<<(M / 128) * (D / 128), 256, 0, stream>>>(hmid, ff2t, out, out, M, D, FFD);
}

// Round 4
// 1033.610 us; speedup vs baseline: 1.5848x; 1.5848x over previous
//
#include <hip/hip_runtime.h>

// ---------------------------------------------------------------------------
// DecoderBlock on MI355X (gfx950).  B=2, L=2048, D=2048, H=16, DH=128, FF=8192
// Round 4: revert attn to R2 single-tile/block (no spills) + state-neutral
// fixes: heavy-first ordering, V double-buffer (T3 minimal), V/P XOR swizzle
// (V pre-swizzled in v_transpose, verified in R3), setprio.  QKV fused into
// one GEMM via EPI=3 split epilogue.
// ---------------------------------------------------------------------------

typedef __bf16 bf16;
typedef __bf16 bf16x8 __attribute__((ext_vector_type(8)));
typedef float  f32x4  __attribute__((ext_vector_type(4)));

__device__ __forceinline__ void gload16(const void* g, void* l) {
  __builtin_amdgcn_global_load_lds((const __attribute__((address_space(1))) void*)g,
                                   (__attribute__((address_space(3))) void*)l,
                                   16, 0, 0);
}

// ------------------------------ RMSNorm (f32 -> bf16) ----------------------
__global__ __launch_bounds__(256) void rmsnorm_to_bf16(
    const float* __restrict__ x, const float* __restrict__ w, bf16* __restrict__ out)
{
  const int D = 2048;
  const int row = blockIdx.x;
  const int tid = threadIdx.x;
  const float* xr = x + (size_t)row * D;
  float4 a = ((const float4*)xr)[tid * 2];
  float4 c = ((const float4*)xr)[tid * 2 + 1];
  float ss = a.x*a.x + a.y*a.y + a.z*a.z + a.w*a.w
           + c.x*c.x + c.y*c.y + c.z*c.z + c.w*c.w;
  #pragma unroll
  for (int m = 1; m < 64; m <<= 1) ss += __shfl_xor(ss, m, 64);
  __shared__ float red[4];
  if ((tid & 63) == 0) red[tid >> 6] = ss;
  __syncthreads();
  float tot = red[0] + red[1] + red[2] + red[3];
  float rms = rsqrtf(tot * (1.0f / D) + 1.1920929e-7f);
  const float* wr = w + tid * 8;
  float vals[8] = {a.x, a.y, a.z, a.w, c.x, c.y, c.z, c.w};
  bf16x8 o;
  #pragma unroll
  for (int j = 0; j < 8; ++j) o[j] = (bf16)(vals[j] * rms * wr[j]);
  *(bf16x8*)(out + (size_t)row * D + tid * 8) = o;
}

// --------------------- transpose + convert f32[R][C] -> bf16[C][R] ---------
__global__ __launch_bounds__(256) void transpose_to_bf16(
    const float* __restrict__ in, bf16* __restrict__ out, int R, int C)
{
  __shared__ float tile[32][33];
  const int tx = threadIdx.x, ty = threadIdx.y;      // 32 x 8
  const int c0 = blockIdx.x * 32, r0 = blockIdx.y * 32;
  #pragma unroll
  for (int i = 0; i < 4; ++i)
    tile[ty + i * 8][tx] = in[(size_t)(r0 + ty + i * 8) * C + c0 + tx];
  __syncthreads();
  #pragma unroll
  for (int i = 0; i < 4; ++i)
    out[(size_t)(c0 + ty + i * 8) * R + r0 + tx] = (bf16)tile[tx][ty + i * 8];
}

// --------------- V[b*L+key][h*128+dh] -> VT[(bh*128+dh)][key'] (bf16) ------
// key' granule-XOR swizzled within each 64-key block (verified in R3):
//   key' = (key & ~63) | ((((key>>3)&7) ^ (dh&7)) << 3) | (key & 7)
__global__ __launch_bounds__(256) void v_transpose(
    const bf16* __restrict__ v, bf16* __restrict__ vt)
{
  const int L = 2048, DM = 2048;
  __shared__ bf16 tile[32][33];
  const int tx = threadIdx.x, ty = threadIdx.y;      // 32 x 8
  const int k0 = blockIdx.x * 32;
  const int d0 = blockIdx.y * 32;
  const int bh = blockIdx.z;
  const int b = bh >> 4, h = bh & 15;
  #pragma unroll
  for (int i = 0; i < 4; ++i)
    tile[ty + i * 8][tx] = v[(size_t)(b * L + k0 + ty + i * 8) * DM + h * 128 + d0 + tx];
  __syncthreads();
  #pragma unroll
  for (int i = 0; i < 4; ++i) {
    const int d = d0 + ty + i * 8;
    const int key = k0 + tx;
    const int keysw = (key & ~63) | (((((key >> 3) & 7) ^ (d & 7)) << 3)) | (key & 7);
    vt[(size_t)(bh * 128 + d) * L + keysw] = tile[tx][ty + i * 8];
  }
}

// ------------------------------ GEMM: C = A[M,K] * Bt[N,K]^T ----------------
// EPI: 0 bf16; 1 f32 + resid; 2 silu bf16; 3 bf16 split q/k/v slabs
template<int EPI>
__global__ __launch_bounds__(256, 2) void gemm_bt(
    const bf16* __restrict__ A, const bf16* __restrict__ Bt,
    void* Cout, const float* resid, int M, int N, int K)
{
  __shared__ bf16 sA[128 * 64];
  __shared__ bf16 sB[128 * 64];

  const int tid = threadIdx.x;
  const int lane = tid & 63;
  const int w = tid >> 6;
  const int wm = w >> 1, wn = w & 1;
  const int lo = lane & 15, hi = lane >> 4;

  const int nbn = N >> 7;
  const int nwg = gridDim.x;
  const int bid = blockIdx.x;
  int swz = bid;
  if ((nwg & 7) == 0) { const int cpx = nwg >> 3; swz = (bid & 7) * cpx + (bid >> 3); }
  const int bm = swz / nbn, bn = swz % nbn;

  const bf16* aptr[4];
  const bf16* bptr[4];
  #pragma unroll
  for (int i = 0; i < 4; ++i) {
    const int g = i * 256 + tid;
    const int row = g >> 3, gr = g & 7;
    aptr[i] = A  + (size_t)(bm * 128 + row) * K + gr * 8;
    bptr[i] = Bt + (size_t)(bn * 128 + row) * K + gr * 8;
  }

  f32x4 acc[4][4] = {};
  const int nkt = K >> 6;
  for (int kt = 0; kt < nkt; ++kt) {
    #pragma unroll
    for (int i = 0; i < 4; ++i) {
      gload16(aptr[i] + kt * 64, &sA[(i * 256 + w * 64) * 8]);
      gload16(bptr[i] + kt * 64, &sB[(i * 256 + w * 64) * 8]);
    }
    __syncthreads();
    #pragma unroll
    for (int ks = 0; ks < 2; ++ks) {
      bf16x8 af[4], bfm[4];
      #pragma unroll
      for (int mi = 0; mi < 4; ++mi)
        af[mi] = *(const bf16x8*)&sA[(wm * 64 + mi * 16 + lo) * 64 + ks * 32 + hi * 8];
      #pragma unroll
      for (int ni = 0; ni < 4; ++ni)
        bfm[ni] = *(const bf16x8*)&sB[(wn * 64 + ni * 16 + lo) * 64 + ks * 32 + hi * 8];
      #pragma unroll
      for (int mi = 0; mi < 4; ++mi)
        #pragma unroll
        for (int ni = 0; ni < 4; ++ni)
          acc[mi][ni] = __builtin_amdgcn_mfma_f32_16x16x32_bf16(af[mi], bfm[ni], acc[mi][ni], 0, 0, 0);
    }
    __syncthreads();
  }

  #pragma unroll
  for (int mi = 0; mi < 4; ++mi) {
    #pragma unroll
    for (int j = 0; j < 4; ++j) {
      const size_t row = (size_t)(bm * 128 + wm * 64 + mi * 16 + hi * 4 + j);
      const size_t ro = row * (size_t)N;
      #pragma unroll
      for (int ni = 0; ni < 4; ++ni) {
        const int col = bn * 128 + wn * 64 + ni * 16 + lo;
        const float v = acc[mi][ni][j];
        if constexpr (EPI == 0) {
          ((bf16*)Cout)[ro + col] = (bf16)v;
        } else if constexpr (EPI == 1) {
          ((float*)Cout)[ro + col] = v + resid[ro + col];
        } else if constexpr (EPI == 2) {
          ((bf16*)Cout)[ro + col] = (bf16)(v / (1.0f + __expf(-v)));
        } else {
          // split qkv: col>>11 selects q/k/v slab (each 4096x2048, XNB apart)
          ((bf16*)Cout)[(size_t)(col >> 11) * 8388608 + row * 2048 + (col & 2047)] = (bf16)v;
        }
      }
    }
  }
}

// ------------------------------ RoPE on q,k (in-place, bf16) ---------------
__global__ __launch_bounds__(256) void rope_qk(
    bf16* q, bf16* k, const float* __restrict__ cs, const float* __restrict__ sn)
{
  const int L = 2048, DM = 2048;
  const int idx = blockIdx.x * 256 + threadIdx.x;
  const int m = idx >> 7;
  const int rem = idx & 127;
  const int h = rem >> 3, t8 = rem & 7;
  const int pos = m & (L - 1);
  const int d0 = t8 * 8;
  const float* cb = cs + (size_t)pos * 128 + d0;
  const float* sb = sn + (size_t)pos * 128 + d0;
  float4 c1a = *(const float4*)(cb);      float4 c1b = *(const float4*)(cb + 4);
  float4 c2a = *(const float4*)(cb + 64); float4 c2b = *(const float4*)(cb + 68);
  float4 s1a = *(const float4*)(sb);      float4 s1b = *(const float4*)(sb + 4);
  float4 s2a = *(const float4*)(sb + 64); float4 s2b = *(const float4*)(sb + 68);
  float c1[8] = {c1a.x,c1a.y,c1a.z,c1a.w,c1b.x,c1b.y,c1b.z,c1b.w};
  float c2[8] = {c2a.x,c2a.y,c2a.z,c2a.w,c2b.x,c2b.y,c2b.z,c2b.w};
  float s1[8] = {s1a.x,s1a.y,s1a.z,s1a.w,s1b.x,s1b.y,s1b.z,s1b.w};
  float s2[8] = {s2a.x,s2a.y,s2a.z,s2a.w,s2b.x,s2b.y,s2b.z,s2b.w};
  const size_t base = (size_t)m * DM + h * 128 + d0;
  #pragma unroll
  for (int t = 0; t < 2; ++t) {
    bf16* buf = t ? k : q;
    bf16x8 x1 = *(bf16x8*)(buf + base);
    bf16x8 x2 = *(bf16x8*)(buf + base + 64);
    bf16x8 o1, o2;
    #pragma unroll
    for (int j = 0; j < 8; ++j) {
      const float a = (float)x1[j], b = (float)x2[j];
      o1[j] = (bf16)(a * c1[j] - b * s1[j]);
      o2[j] = (bf16)(b * c2[j] + a * s2[j]);
    }
    *(bf16x8*)(buf + base) = o1;
    *(bf16x8*)(buf + base + 64) = o2;
  }
}

// ------------------------------ Flash attention ----------------------------
// grid (32, B*H), 256 thr.  tile = 31 - blockIdx.x (heavy-first).
// Wave w owns 16 q-rows.  V double-buffered, granule-XOR swizzled (pre-applied
// in VT).  P per-wave LDS, same XOR involution.  One barrier per iteration.
__global__ __launch_bounds__(256, 2) void attn_fwd(
    const bf16* __restrict__ Q, const bf16* __restrict__ Kb,
    const bf16* __restrict__ VT, const int* __restrict__ mask,
    bf16* __restrict__ O)
{
  const int L = 2048, DM = 2048;
  __shared__ bf16 Vt[2][128 * 64];     // [buf][dh][key'], swizzled granules
  __shared__ bf16 Plds[4][16 * 64];    // per-wave P, swizzled granules

  const int tid = threadIdx.x, lane = tid & 63, w = tid >> 6;
  const int lo = lane & 15, hi = lane >> 4;
  const int s7 = lo & 7;
  const int tile = 31 - (int)blockIdx.x;     // heavy-first
  const int bh = blockIdx.y;
  const int b = bh >> 4, h = bh & 15;
  const int qrow = tile * 64 + w * 16;
  const float scale = 0.08838834764831845f;
  const float NEG_INF = -__builtin_inff();

  bf16x8 qf[4];
  {
    const bf16* qb = Q + (size_t)(b * L + qrow + lo) * DM + h * 128;
    #pragma unroll
    for (int ds = 0; ds < 4; ++ds) qf[ds] = *(const bf16x8*)(qb + ds * 32 + hi * 8);
  }

  float mrow[4] = {NEG_INF, NEG_INF, NEG_INF, NEG_INF};
  float lrow[4] = {0.f, 0.f, 0.f, 0.f};
  f32x4 oacc[8] = {};

  const bf16* vsrc[4];
  #pragma unroll
  for (int i = 0; i < 4; ++i) {
    const int g = i * 256 + tid;
    const int row = g >> 3, gr = g & 7;
    vsrc[i] = VT + (size_t)(bh * 128 + row) * L + gr * 8;
  }

  // prologue: stage kt=0 into buf 0
  #pragma unroll
  for (int i = 0; i < 4; ++i)
    gload16(vsrc[i], &Vt[0][(i * 256 + w * 64) * 8]);
  __syncthreads();

  const int nkt = tile + 1;
  for (int kt = 0; kt < nkt; ++kt) {
    const int buf = kt & 1;
    if (kt + 1 < nkt) {
      #pragma unroll
      for (int i = 0; i < 4; ++i)
        gload16(vsrc[i] + (kt + 1) * 64, &Vt[buf ^ 1][(i * 256 + w * 64) * 8]);
    }

    int mk[4];
    #pragma unroll
    for (int kb = 0; kb < 4; ++kb) mk[kb] = mask[b * L + kt * 64 + kb * 16 + lo];

    // ---- QK^T (K frags direct from global/L2) ----
    f32x4 S[4];
    const bf16* kbase = Kb + (size_t)(b * L + kt * 64 + lo) * DM + h * 128 + hi * 8;
    __builtin_amdgcn_s_setprio(1);
    #pragma unroll
    for (int kb = 0; kb < 4; ++kb) {
      bf16x8 kf[4];
      #pragma unroll
      for (int ds = 0; ds < 4; ++ds)
        kf[ds] = *(const bf16x8*)(kbase + (size_t)kb * 16 * DM + ds * 32);
      f32x4 s = {};
      #pragma unroll
      for (int ds = 0; ds < 4; ++ds)
        s = __builtin_amdgcn_mfma_f32_16x16x32_bf16(qf[ds], kf[ds], s, 0, 0, 0);
      S[kb] = s;
    }
    __builtin_amdgcn_s_setprio(0);

    // ---- scale + causal + mask ----
    #pragma unroll
    for (int kb = 0; kb < 4; ++kb) {
      const int kidx = kt * 64 + kb * 16 + lo;
      #pragma unroll
      for (int j = 0; j < 4; ++j) {
        const float sv = S[kb][j] * scale;
        S[kb][j] = (mk[kb] != 0 && kidx <= qrow + hi * 4 + j) ? sv : NEG_INF;
      }
    }

    // ---- online softmax ----
    float p[4][4];
    #pragma unroll
    for (int j = 0; j < 4; ++j) {
      float tm = fmaxf(fmaxf(S[0][j], S[1][j]), fmaxf(S[2][j], S[3][j]));
      tm = fmaxf(tm, __shfl_xor(tm, 1, 64));
      tm = fmaxf(tm, __shfl_xor(tm, 2, 64));
      tm = fmaxf(tm, __shfl_xor(tm, 4, 64));
      tm = fmaxf(tm, __shfl_xor(tm, 8, 64));
      const float mn = fmaxf(mrow[j], tm);
      const float mn2 = (mn == NEG_INF) ? 0.f : mn;
      const float alpha = __expf(mrow[j] - mn2);
      float ps = 0.f;
      #pragma unroll
      for (int kb = 0; kb < 4; ++kb) { p[kb][j] = __expf(S[kb][j] - mn2); ps += p[kb][j]; }
      ps += __shfl_xor(ps, 1, 64);
      ps += __shfl_xor(ps, 2, 64);
      ps += __shfl_xor(ps, 4, 64);
      ps += __shfl_xor(ps, 8, 64);
      lrow[j] = lrow[j] * alpha + ps;
      mrow[j] = mn;
      #pragma unroll
      for (int n = 0; n < 8; ++n) oacc[n][j] *= alpha;
    }

    // ---- P -> per-wave LDS (XOR-swizzled granules) ----
    #pragma unroll
    for (int kb = 0; kb < 4; ++kb)
      #pragma unroll
      for (int j = 0; j < 4; ++j) {
        const int row = hi * 4 + j;
        Plds[w][row * 64 + ((((kb * 2 + (lo >> 3)) ^ (row & 7))) << 3) + (lo & 7)] = (bf16)p[kb][j];
      }

    // ---- PV: shared-swizzle reads ----
    __builtin_amdgcn_s_setprio(1);
    #pragma unroll
    for (int ks = 0; ks < 2; ++ks) {
      const bf16x8 pa = *(const bf16x8*)&Plds[w][lo * 64 + (((ks * 4 + hi) ^ s7) << 3)];
      #pragma unroll
      for (int n = 0; n < 8; ++n) {
        const int r = n * 16 + lo;
        const bf16x8 vf = *(const bf16x8*)&Vt[buf][r * 64 + (((ks * 4 + hi) ^ s7) << 3)];
        oacc[n] = __builtin_amdgcn_mfma_f32_16x16x32_bf16(pa, vf, oacc[n], 0, 0, 0);
      }
    }
    __builtin_amdgcn_s_setprio(0);

    __syncthreads();
  }

  float inv[4];
  #pragma unroll
  for (int j = 0; j < 4; ++j) inv[j] = (lrow[j] > 0.f) ? 1.f / lrow[j] : 0.f;
  bf16* ob = O + (size_t)(b * L + qrow) * DM + h * 128;
  #pragma unroll
  for (int n = 0; n < 8; ++n)
    #pragma unroll
    for (int j = 0; j < 4; ++j)
      ob[(size_t)(hi * 4 + j) * DM + n * 16 + lo] = (bf16)(oacc[n][j] * inv[j]);
}

// ---------------------------------------------------------------------------
extern "C" void kernel_launch(void* const* d_in, const int* in_sizes, int n_in,
                              void* d_out, int out_size, void* d_ws, size_t ws_size,
                              hipStream_t stream)
{
  (void)in_sizes; (void)n_in; (void)out_size; (void)ws_size;
  const float* x        = (const float*)d_in[0];
  const float* rope_cos = (const float*)d_in[1];
  const float* rope_sin = (const float*)d_in[2];
  const int*   mask     = (const int*)d_in[3];
  const float* w_norm1  = (const float*)d_in[4];
  const float* w_norm2  = (const float*)d_in[5];
  const float* wq       = (const float*)d_in[6];
  const float* wk       = (const float*)d_in[7];
  const float* wv       = (const float*)d_in[8];
  const float* wo       = (const float*)d_in[9];
  const float* w_ff1    = (const float*)d_in[10];
  const float* w_ff2    = (const float*)d_in[11];
  float* out = (float*)d_out;

  const int M = 4096, D = 2048, FFD = 8192;
  char* ws = (char*)d_ws;
  const size_t WSLAB = 8388608ull;    // 2048*2048*2 B
  const size_t XNB   = 16777216ull;   // 4096*2048*2 B
  bf16* wqt  = (bf16*)(ws);           // wqt|wkt|wvt contiguous = [6144][2048]
  bf16* wkt  = (bf16*)(ws + WSLAB);
  bf16* wvt  = (bf16*)(ws + 2 * WSLAB);
  bf16* wot  = (bf16*)(ws + 3 * WSLAB);
  char* pool = ws + 4 * WSLAB;
  bf16* xn   = (bf16*)(pool);
  bf16* qb   = (bf16*)(pool + XNB);
  bf16* kb   = (bf16*)(pool + 2 * XNB);
  bf16* vb   = (bf16*)(pool + 3 * XNB);
  bf16* ao   = (bf16*)(pool + 4 * XNB);
  bf16* vt   = (bf16*)(pool);               // reuses xn after QKV GEMM
  bf16* ff1t = (bf16*)(ws);                 // reuses wq_t..wo_t after WO GEMM
  bf16* hmid = (bf16*)(pool);               // reuses vt|qb|kb|vb after attention
  bf16* ff2t = (bf16*)(ws);                 // reuses ff1_t after FF1
  bf16* xn2  = (bf16*)(pool + 4 * XNB);     // reuses ao after WO GEMM

  const dim3 tb(32, 8);

  rmsnorm_to_bf16<<<M, 256, 0, stream>>>(x, w_norm1, xn);
  transpose_to_bf16<<<dim3(D / 32, D / 32), tb, 0, stream>>>(wq, wqt, D, D);
  transpose_to_bf16<<<dim3(D / 32, D / 32), tb, 0, stream>>>(wk, wkt, D, D);
  transpose_to_bf16<<<dim3(D / 32, D / 32), tb, 0, stream>>>(wv, wvt, D, D);
  transpose_to_bf16<<<dim3(D / 32, D / 32), tb, 0, stream>>>(wo, wot, D, D);

  // fused QKV: Bt = [6144][2048], epilogue splits into qb/kb/vb slabs
  gemm_bt<3><<<(M / 128) * (6144 / 128), 256, 0, stream>>>(xn, wqt, qb, nullptr, M, 6144, D);

  rope_qk<<<2048, 256, 0, stream>>>(qb, kb, rope_cos, rope_sin);

  // xn dead from here; vt overwrites it
  v_transpose<<<dim3(2048 / 32, 128 / 32, 32), tb, 0, stream>>>(vb, vt);

  attn_fwd<<<dim3(32, 32), 256, 0, stream>>>(qb, kb, vt, mask, ao);

  gemm_bt<1><<<(M / 128) * (D / 128), 256, 0, stream>>>(ao, wot, out, x, M, D, D);

  rmsnorm_to_bf16<<<M, 256, 0, stream>>>(out, w_norm2, xn2);

  transpose_to_bf16<<<dim3(FFD / 32, D / 32), tb, 0, stream>>>(w_ff1, ff1t, D, FFD);
  gemm_bt<2><<<(M / 128) * (FFD / 128), 256, 0, stream>>>(xn2, ff1t, hmid, nullptr, M, FFD, D);

  transpose_to_bf16<<<dim3(D / 32, FFD / 32), tb, 0, stream>>>(w_ff2, ff2t, FFD, D);
  gemm_bt<1><<<(M / 128) * (D / 128), 256, 0, stream>>>(hmid, ff2t, out, out, M, D, FFD);
}

// Round 5
// 796.283 us; speedup vs baseline: 2.0572x; 1.2980x over previous
//
#include <hip/hip_runtime.h>

// ---------------------------------------------------------------------------
// DecoderBlock on MI355X (gfx950).  B=2, L=2048, D=2048, H=16, DH=128, FF=8192
// Round 5: attn loop has NO in-loop global K loads: K staged via LDS (dbuf)
// with source-side granule swizzle written by rope; V staged as before.
// XCD-grouped 1-D dispatch (all tiles of a bh on one XCD), heavy-first.
// One barrier per iteration (T3 minimal).  GEMMs unchanged (R2/R4-verified).
// ---------------------------------------------------------------------------

typedef __bf16 bf16;
typedef __bf16 bf16x8 __attribute__((ext_vector_type(8)));
typedef float  f32x4  __attribute__((ext_vector_type(4)));

__device__ __forceinline__ void gload16(const void* g, void* l) {
  __builtin_amdgcn_global_load_lds((const __attribute__((address_space(1))) void*)g,
                                   (__attribute__((address_space(3))) void*)l,
                                   16, 0, 0);
}

// ------------------------------ RMSNorm (f32 -> bf16) ----------------------
__global__ __launch_bounds__(256) void rmsnorm_to_bf16(
    const float* __restrict__ x, const float* __restrict__ w, bf16* __restrict__ out)
{
  const int D = 2048;
  const int row = blockIdx.x;
  const int tid = threadIdx.x;
  const float* xr = x + (size_t)row * D;
  float4 a = ((const float4*)xr)[tid * 2];
  float4 c = ((const float4*)xr)[tid * 2 + 1];
  float ss = a.x*a.x + a.y*a.y + a.z*a.z + a.w*a.w
           + c.x*c.x + c.y*c.y + c.z*c.z + c.w*c.w;
  #pragma unroll
  for (int m = 1; m < 64; m <<= 1) ss += __shfl_xor(ss, m, 64);
  __shared__ float red[4];
  if ((tid & 63) == 0) red[tid >> 6] = ss;
  __syncthreads();
  float tot = red[0] + red[1] + red[2] + red[3];
  float rms = rsqrtf(tot * (1.0f / D) + 1.1920929e-7f);
  const float* wr = w + tid * 8;
  float vals[8] = {a.x, a.y, a.z, a.w, c.x, c.y, c.z, c.w};
  bf16x8 o;
  #pragma unroll
  for (int j = 0; j < 8; ++j) o[j] = (bf16)(vals[j] * rms * wr[j]);
  *(bf16x8*)(out + (size_t)row * D + tid * 8) = o;
}

// --------------------- transpose + convert f32[R][C] -> bf16[C][R] ---------
__global__ __launch_bounds__(256) void transpose_to_bf16(
    const float* __restrict__ in, bf16* __restrict__ out, int R, int C)
{
  __shared__ float tile[32][33];
  const int tx = threadIdx.x, ty = threadIdx.y;      // 32 x 8
  const int c0 = blockIdx.x * 32, r0 = blockIdx.y * 32;
  #pragma unroll
  for (int i = 0; i < 4; ++i)
    tile[ty + i * 8][tx] = in[(size_t)(r0 + ty + i * 8) * C + c0 + tx];
  __syncthreads();
  #pragma unroll
  for (int i = 0; i < 4; ++i)
    out[(size_t)(c0 + ty + i * 8) * R + r0 + tx] = (bf16)tile[tx][ty + i * 8];
}

// --------------- V[b*L+key][h*128+dh] -> VT[(bh*128+dh)][key'] (bf16) ------
// key' granule-XOR swizzled within each 64-key block (verified R3/R4):
//   key' = (key & ~63) | ((((key>>3)&7) ^ (dh&7)) << 3) | (key & 7)
__global__ __launch_bounds__(256) void v_transpose(
    const bf16* __restrict__ v, bf16* __restrict__ vt)
{
  const int L = 2048, DM = 2048;
  __shared__ bf16 tile[32][33];
  const int tx = threadIdx.x, ty = threadIdx.y;      // 32 x 8
  const int k0 = blockIdx.x * 32;
  const int d0 = blockIdx.y * 32;
  const int bh = blockIdx.z;
  const int b = bh >> 4, h = bh & 15;
  #pragma unroll
  for (int i = 0; i < 4; ++i)
    tile[ty + i * 8][tx] = v[(size_t)(b * L + k0 + ty + i * 8) * DM + h * 128 + d0 + tx];
  __syncthreads();
  #pragma unroll
  for (int i = 0; i < 4; ++i) {
    const int d = d0 + ty + i * 8;
    const int key = k0 + tx;
    const int keysw = (key & ~63) | (((((key >> 3) & 7) ^ (d & 7)) << 3)) | (key & 7);
    vt[(size_t)(bh * 128 + d) * L + keysw] = tile[tx][ty + i * 8];
  }
}

// ------------------------------ GEMM: C = A[M,K] * Bt[N,K]^T ----------------
// EPI: 0 bf16; 1 f32 + resid; 2 silu bf16; 3 bf16 split q/k/v slabs
template<int EPI>
__global__ __launch_bounds__(256, 2) void gemm_bt(
    const bf16* __restrict__ A, const bf16* __restrict__ Bt,
    void* Cout, const float* resid, int M, int N, int K)
{
  __shared__ bf16 sA[128 * 64];
  __shared__ bf16 sB[128 * 64];

  const int tid = threadIdx.x;
  const int lane = tid & 63;
  const int w = tid >> 6;
  const int wm = w >> 1, wn = w & 1;
  const int lo = lane & 15, hi = lane >> 4;

  const int nbn = N >> 7;
  const int nwg = gridDim.x;
  const int bid = blockIdx.x;
  int swz = bid;
  if ((nwg & 7) == 0) { const int cpx = nwg >> 3; swz = (bid & 7) * cpx + (bid >> 3); }
  const int bm = swz / nbn, bn = swz % nbn;

  const bf16* aptr[4];
  const bf16* bptr[4];
  #pragma unroll
  for (int i = 0; i < 4; ++i) {
    const int g = i * 256 + tid;
    const int row = g >> 3, gr = g & 7;
    aptr[i] = A  + (size_t)(bm * 128 + row) * K + gr * 8;
    bptr[i] = Bt + (size_t)(bn * 128 + row) * K + gr * 8;
  }

  f32x4 acc[4][4] = {};
  const int nkt = K >> 6;
  for (int kt = 0; kt < nkt; ++kt) {
    #pragma unroll
    for (int i = 0; i < 4; ++i) {
      gload16(aptr[i] + kt * 64, &sA[(i * 256 + w * 64) * 8]);
      gload16(bptr[i] + kt * 64, &sB[(i * 256 + w * 64) * 8]);
    }
    __syncthreads();
    #pragma unroll
    for (int ks = 0; ks < 2; ++ks) {
      bf16x8 af[4], bfm[4];
      #pragma unroll
      for (int mi = 0; mi < 4; ++mi)
        af[mi] = *(const bf16x8*)&sA[(wm * 64 + mi * 16 + lo) * 64 + ks * 32 + hi * 8];
      #pragma unroll
      for (int ni = 0; ni < 4; ++ni)
        bfm[ni] = *(const bf16x8*)&sB[(wn * 64 + ni * 16 + lo) * 64 + ks * 32 + hi * 8];
      #pragma unroll
      for (int mi = 0; mi < 4; ++mi)
        #pragma unroll
        for (int ni = 0; ni < 4; ++ni)
          acc[mi][ni] = __builtin_amdgcn_mfma_f32_16x16x32_bf16(af[mi], bfm[ni], acc[mi][ni], 0, 0, 0);
    }
    __syncthreads();
  }

  #pragma unroll
  for (int mi = 0; mi < 4; ++mi) {
    #pragma unroll
    for (int j = 0; j < 4; ++j) {
      const size_t row = (size_t)(bm * 128 + wm * 64 + mi * 16 + hi * 4 + j);
      const size_t ro = row * (size_t)N;
      #pragma unroll
      for (int ni = 0; ni < 4; ++ni) {
        const int col = bn * 128 + wn * 64 + ni * 16 + lo;
        const float v = acc[mi][ni][j];
        if constexpr (EPI == 0) {
          ((bf16*)Cout)[ro + col] = (bf16)v;
        } else if constexpr (EPI == 1) {
          ((float*)Cout)[ro + col] = v + resid[ro + col];
        } else if constexpr (EPI == 2) {
          ((bf16*)Cout)[ro + col] = (bf16)(v / (1.0f + __expf(-v)));
        } else {
          ((bf16*)Cout)[(size_t)(col >> 11) * 8388608 + row * 2048 + (col & 2047)] = (bf16)v;
        }
      }
    }
  }
}

// ------------------- RoPE: q in-place; k -> kswz with granule swizzle ------
// kswz row = same row m; within head slice, dh-granule g (of 16) written at
// position g ^ (pos & 15)  (involution; makes attn's LDS K-tile reads
// conflict-free after linear global_load_lds staging).
__global__ __launch_bounds__(256) void rope_qk(
    bf16* q, const bf16* __restrict__ k, bf16* __restrict__ kswz,
    const float* __restrict__ cs, const float* __restrict__ sn)
{
  const int L = 2048, DM = 2048;
  const int idx = blockIdx.x * 256 + threadIdx.x;
  const int m = idx >> 7;
  const int rem = idx & 127;
  const int h = rem >> 3, t8 = rem & 7;
  const int pos = m & (L - 1);
  const int d0 = t8 * 8;
  const float* cb = cs + (size_t)pos * 128 + d0;
  const float* sb = sn + (size_t)pos * 128 + d0;
  float4 c1a = *(const float4*)(cb);      float4 c1b = *(const float4*)(cb + 4);
  float4 c2a = *(const float4*)(cb + 64); float4 c2b = *(const float4*)(cb + 68);
  float4 s1a = *(const float4*)(sb);      float4 s1b = *(const float4*)(sb + 4);
  float4 s2a = *(const float4*)(sb + 64); float4 s2b = *(const float4*)(sb + 68);
  float c1[8] = {c1a.x,c1a.y,c1a.z,c1a.w,c1b.x,c1b.y,c1b.z,c1b.w};
  float c2[8] = {c2a.x,c2a.y,c2a.z,c2a.w,c2b.x,c2b.y,c2b.z,c2b.w};
  float s1[8] = {s1a.x,s1a.y,s1a.z,s1a.w,s1b.x,s1b.y,s1b.z,s1b.w};
  float s2[8] = {s2a.x,s2a.y,s2a.z,s2a.w,s2b.x,s2b.y,s2b.z,s2b.w};
  const size_t base = (size_t)m * DM + h * 128 + d0;

  // q in-place
  {
    bf16x8 x1 = *(bf16x8*)(q + base);
    bf16x8 x2 = *(bf16x8*)(q + base + 64);
    bf16x8 o1, o2;
    #pragma unroll
    for (int j = 0; j < 8; ++j) {
      const float a = (float)x1[j], b = (float)x2[j];
      o1[j] = (bf16)(a * c1[j] - b * s1[j]);
      o2[j] = (bf16)(b * c2[j] + a * s2[j]);
    }
    *(bf16x8*)(q + base) = o1;
    *(bf16x8*)(q + base + 64) = o2;
  }
  // k -> kswz (swizzled granule positions within the head slice)
  {
    bf16x8 x1 = *(const bf16x8*)(k + base);
    bf16x8 x2 = *(const bf16x8*)(k + base + 64);
    bf16x8 o1, o2;
    #pragma unroll
    for (int j = 0; j < 8; ++j) {
      const float a = (float)x1[j], b = (float)x2[j];
      o1[j] = (bf16)(a * c1[j] - b * s1[j]);
      o2[j] = (bf16)(b * c2[j] + a * s2[j]);
    }
    const int s = pos & 15;
    const int p1 = t8 ^ s;
    const int p2 = (8 + t8) ^ s;
    bf16* kr = kswz + (size_t)m * DM + h * 128;
    *(bf16x8*)(kr + p1 * 8) = o1;
    *(bf16x8*)(kr + p2 * 8) = o2;
  }
}

// ------------------------------ Flash attention ----------------------------
// grid 1024 (1-D), 256 thr.  n -> xcd = n&7, slot = n>>3;
//   bh = xcd + 8*(slot>>5)  (all 32 tiles of a bh on one XCD, L2-friendly)
//   tile = 31 - (slot&31)   (heavy-first within group)
// K and V both double-buffered in LDS (source-side swizzles), 1 barrier/iter.
__global__ __launch_bounds__(256, 2) void attn_fwd(
    const bf16* __restrict__ Q, const bf16* __restrict__ Kswz,
    const bf16* __restrict__ VT, const int* __restrict__ mask,
    bf16* __restrict__ O)
{
  const int L = 2048, DM = 2048;
  __shared__ bf16 Kt[2][64 * 128];     // [buf][key][dh'], granule dh' = g ^ (key&15)
  __shared__ bf16 Vt[2][128 * 64];     // [buf][dh][key'], granule key' = g ^ (dh&7)
  __shared__ bf16 Plds[4][16 * 64];    // per-wave P, granule-XOR swizzled

  const int tid = threadIdx.x, lane = tid & 63, w = tid >> 6;
  const int lo = lane & 15, hi = lane >> 4;
  const int s7 = lo & 7;
  const int n = blockIdx.x;
  const int xcd = n & 7, slot = n >> 3;
  const int bh = xcd + 8 * (slot >> 5);
  const int tile = 31 - (slot & 31);
  const int b = bh >> 4, h = bh & 15;
  const int qrow = tile * 64 + w * 16;
  const float scale = 0.08838834764831845f;
  const float NEG_INF = -__builtin_inff();

  bf16x8 qf[4];
  {
    const bf16* qb = Q + (size_t)(b * L + qrow + lo) * DM + h * 128;
    #pragma unroll
    for (int ds = 0; ds < 4; ++ds) qf[ds] = *(const bf16x8*)(qb + ds * 32 + hi * 8);
  }

  float mrow[4] = {NEG_INF, NEG_INF, NEG_INF, NEG_INF};
  float lrow[4] = {0.f, 0.f, 0.f, 0.f};
  f32x4 oacc[8] = {};

  // staging sources
  const bf16* vsrc[4];   // V: granule g -> (dh = g>>3, key8 = g&7)
  const bf16* ksrc[4];   // K: granule g -> (key = g>>4, dh16 = g&15)
  #pragma unroll
  for (int i = 0; i < 4; ++i) {
    const int gv = i * 256 + tid;
    vsrc[i] = VT + (size_t)(bh * 128 + (gv >> 3)) * L + (gv & 7) * 8;
    const int gk = i * 256 + tid;
    ksrc[i] = Kswz + (size_t)(b * L + (gk >> 4)) * DM + h * 128 + (gk & 15) * 8;
  }

  // prologue: stage kt=0 into buf 0
  #pragma unroll
  for (int i = 0; i < 4; ++i) {
    gload16(ksrc[i], &Kt[0][(i * 256 + w * 64) * 8]);
    gload16(vsrc[i], &Vt[0][(i * 256 + w * 64) * 8]);
  }
  __syncthreads();

  const int nkt = tile + 1;
  for (int kt = 0; kt < nkt; ++kt) {
    const int buf = kt & 1;
    if (kt + 1 < nkt) {
      #pragma unroll
      for (int i = 0; i < 4; ++i) {
        gload16(ksrc[i] + (size_t)(kt + 1) * 64 * DM, &Kt[buf ^ 1][(i * 256 + w * 64) * 8]);
        gload16(vsrc[i] + (kt + 1) * 64,              &Vt[buf ^ 1][(i * 256 + w * 64) * 8]);
      }
    }

    int mk[4];
    #pragma unroll
    for (int kb = 0; kb < 4; ++kb) mk[kb] = mask[b * L + kt * 64 + kb * 16 + lo];

    // ---- QK^T from LDS K (conflict-free via source swizzle) ----
    f32x4 S[4];
    __builtin_amdgcn_s_setprio(1);
    #pragma unroll
    for (int kb = 0; kb < 4; ++kb) {
      f32x4 s = {};
      #pragma unroll
      for (int ds = 0; ds < 4; ++ds) {
        const bf16x8 kf = *(const bf16x8*)&Kt[buf][(kb * 16 + lo) * 128 + (((ds * 4 + hi) ^ lo) * 8)];
        s = __builtin_amdgcn_mfma_f32_16x16x32_bf16(qf[ds], kf, s, 0, 0, 0);
      }
      S[kb] = s;
    }
    __builtin_amdgcn_s_setprio(0);

    // ---- scale + causal + mask ----
    #pragma unroll
    for (int kb = 0; kb < 4; ++kb) {
      const int kidx = kt * 64 + kb * 16 + lo;
      #pragma unroll
      for (int j = 0; j < 4; ++j) {
        const float sv = S[kb][j] * scale;
        S[kb][j] = (mk[kb] != 0 && kidx <= qrow + hi * 4 + j) ? sv : NEG_INF;
      }
    }

    // ---- online softmax ----
    float p[4][4];
    #pragma unroll
    for (int j = 0; j < 4; ++j) {
      float tm = fmaxf(fmaxf(S[0][j], S[1][j]), fmaxf(S[2][j], S[3][j]));
      tm = fmaxf(tm, __shfl_xor(tm, 1, 64));
      tm = fmaxf(tm, __shfl_xor(tm, 2, 64));
      tm = fmaxf(tm, __shfl_xor(tm, 4, 64));
      tm = fmaxf(tm, __shfl_xor(tm, 8, 64));
      const float mn = fmaxf(mrow[j], tm);
      const float mn2 = (mn == NEG_INF) ? 0.f : mn;
      const float alpha = __expf(mrow[j] - mn2);
      float ps = 0.f;
      #pragma unroll
      for (int kb = 0; kb < 4; ++kb) { p[kb][j] = __expf(S[kb][j] - mn2); ps += p[kb][j]; }
      ps += __shfl_xor(ps, 1, 64);
      ps += __shfl_xor(ps, 2, 64);
      ps += __shfl_xor(ps, 4, 64);
      ps += __shfl_xor(ps, 8, 64);
      lrow[j] = lrow[j] * alpha + ps;
      mrow[j] = mn;
      #pragma unroll
      for (int n2 = 0; n2 < 8; ++n2) oacc[n2][j] *= alpha;
    }

    // ---- P -> per-wave LDS (XOR-swizzled granules) ----
    #pragma unroll
    for (int kb = 0; kb < 4; ++kb)
      #pragma unroll
      for (int j = 0; j < 4; ++j) {
        const int row = hi * 4 + j;
        Plds[w][row * 64 + ((((kb * 2 + (lo >> 3)) ^ (row & 7))) << 3) + (lo & 7)] = (bf16)p[kb][j];
      }

    // ---- PV ----
    __builtin_amdgcn_s_setprio(1);
    #pragma unroll
    for (int ks = 0; ks < 2; ++ks) {
      const bf16x8 pa = *(const bf16x8*)&Plds[w][lo * 64 + (((ks * 4 + hi) ^ s7) << 3)];
      #pragma unroll
      for (int n2 = 0; n2 < 8; ++n2) {
        const int r = n2 * 16 + lo;
        const bf16x8 vf = *(const bf16x8*)&Vt[buf][r * 64 + (((ks * 4 + hi) ^ s7) << 3)];
        oacc[n2] = __builtin_amdgcn_mfma_f32_16x16x32_bf16(pa, vf, oacc[n2], 0, 0, 0);
      }
    }
    __builtin_amdgcn_s_setprio(0);

    __syncthreads();
  }

  float inv[4];
  #pragma unroll
  for (int j = 0; j < 4; ++j) inv[j] = (lrow[j] > 0.f) ? 1.f / lrow[j] : 0.f;
  bf16* ob = O + (size_t)(b * L + qrow) * DM + h * 128;
  #pragma unroll
  for (int n2 = 0; n2 < 8; ++n2)
    #pragma unroll
    for (int j = 0; j < 4; ++j)
      ob[(size_t)(hi * 4 + j) * DM + n2 * 16 + lo] = (bf16)(oacc[n2][j] * inv[j]);
}

// ---------------------------------------------------------------------------
extern "C" void kernel_launch(void* const* d_in, const int* in_sizes, int n_in,
                              void* d_out, int out_size, void* d_ws, size_t ws_size,
                              hipStream_t stream)
{
  (void)in_sizes; (void)n_in; (void)out_size; (void)ws_size;
  const float* x        = (const float*)d_in[0];
  const float* rope_cos = (const float*)d_in[1];
  const float* rope_sin = (const float*)d_in[2];
  const int*   mask     = (const int*)d_in[3];
  const float* w_norm1  = (const float*)d_in[4];
  const float* w_norm2  = (const float*)d_in[5];
  const float* wq       = (const float*)d_in[6];
  const float* wk       = (const float*)d_in[7];
  const float* wv       = (const float*)d_in[8];
  const float* wo       = (const float*)d_in[9];
  const float* w_ff1    = (const float*)d_in[10];
  const float* w_ff2    = (const float*)d_in[11];
  float* out = (float*)d_out;

  const int M = 4096, D = 2048, FFD = 8192;
  char* ws = (char*)d_ws;
  const size_t WSLAB = 8388608ull;    // 2048*2048*2 B
  const size_t XNB   = 16777216ull;   // 4096*2048*2 B
  bf16* wqt  = (bf16*)(ws);           // wqt|wkt|wvt contiguous = [6144][2048]
  bf16* wkt  = (bf16*)(ws + WSLAB);
  bf16* wvt  = (bf16*)(ws + 2 * WSLAB);
  bf16* wot  = (bf16*)(ws + 3 * WSLAB);
  char* pool = ws + 4 * WSLAB;
  bf16* xn   = (bf16*)(pool);
  bf16* qb   = (bf16*)(pool + XNB);
  bf16* kb   = (bf16*)(pool + 2 * XNB);
  bf16* vb   = (bf16*)(pool + 3 * XNB);
  bf16* ao   = (bf16*)(pool + 4 * XNB);
  bf16* vt   = (bf16*)(pool);               // reuses xn after QKV GEMM
  bf16* kswz = (bf16*)(pool + 3 * XNB);     // reuses vb after v_transpose
  bf16* ff1t = (bf16*)(ws);                 // reuses wq_t..wo_t after WO GEMM
  bf16* hmid = (bf16*)(pool);               // reuses vt|qb|kb after attention
  bf16* ff2t = (bf16*)(ws);                 // reuses ff1_t after FF1
  bf16* xn2  = (bf16*)(pool + 4 * XNB);     // reuses ao after WO GEMM

  const dim3 tb(32, 8);

  rmsnorm_to_bf16<<<M, 256, 0, stream>>>(x, w_norm1, xn);
  transpose_to_bf16<<<dim3(D / 32, D / 32), tb, 0, stream>>>(wq, wqt, D, D);
  transpose_to_bf16<<<dim3(D / 32, D / 32), tb, 0, stream>>>(wk, wkt, D, D);
  transpose_to_bf16<<<dim3(D / 32, D / 32), tb, 0, stream>>>(wv, wvt, D, D);
  transpose_to_bf16<<<dim3(D / 32, D / 32), tb, 0, stream>>>(wo, wot, D, D);

  // fused QKV: Bt = [6144][2048], epilogue splits into qb/kb/vb slabs
  gemm_bt<3><<<(M / 128) * (6144 / 128), 256, 0, stream>>>(xn, wqt, qb, nullptr, M, 6144, D);

  // xn dead after QKV GEMM; vt overwrites it
  v_transpose<<<dim3(2048 / 32, 128 / 32, 32), tb, 0, stream>>>(vb, vt);

  // vb dead after v_transpose; kswz overwrites it
  rope_qk<<<2048, 256, 0, stream>>>(qb, kb, kswz, rope_cos, rope_sin);

  attn_fwd<<<1024, 256, 0, stream>>>(qb, kswz, vt, mask, ao);

  gemm_bt<1><<<(M / 128) * (D / 128), 256, 0, stream>>>(ao, wot, out, x, M, D, D);

  rmsnorm_to_bf16<<<M, 256, 0, stream>>>(out, w_norm2, xn2);

  transpose_to_bf16<<<dim3(FFD / 32, D / 32), tb, 0, stream>>>(w_ff1, ff1t, D, FFD);
  gemm_bt<2><<<(M / 128) * (FFD / 128), 256, 0, stream>>>(xn2, ff1t, hmid, nullptr, M, FFD, D);

  transpose_to_bf16<<<dim3(D / 32, FFD / 32), tb, 0, stream>>>(w_ff2, ff2t, FFD, D);
  gemm_bt<1><<<(M / 128) * (D / 128), 256, 0, stream>>>(hmid, ff2t, out, out, M, D, FFD);
}